// Round 2
// baseline (364.135 us; speedup 1.0000x reference)
//
#include <hip/hip_runtime.h>

// DistMult: out[n1,n2] = (input1 * w[type]) @ input2^T + bias
// n1=n2=8192, d=512, fp32 in/out. Strategy: fp32->bf16 convert (w_r scale fused),
// then bf16 MFMA NT-GEMM (128x128 tile, BK=64, global_load_lds 16B,
// XCD-aware block swizzle for L2 residency of B panels).

#define N1 8192
#define N2 8192
#define DK 512
#define BM 128
#define BN 128
#define BK 64

typedef short bf16x8 __attribute__((ext_vector_type(8)));
typedef float f32x4 __attribute__((ext_vector_type(4)));

__device__ __forceinline__ unsigned short f2bf(float f) {
    unsigned int u = __float_as_uint(f);
    u = (u + 0x7FFFu + ((u >> 16) & 1u)) >> 16;  // round-to-nearest-even
    return (unsigned short)u;
}

// One pass over both inputs: A-region gets w_r scaling, B-region straight cast.
__global__ __launch_bounds__(256) void convert_kernel(
        const float* __restrict__ in1, const float* __restrict__ in2,
        const float* __restrict__ weight, const int* __restrict__ type_index,
        unsigned short* __restrict__ a_bf, unsigned short* __restrict__ b_bf) {
    const int QA = N1 * DK / 4;
    int i = blockIdx.x * blockDim.x + threadIdx.x;
    if (i < QA) {
        float4 v = reinterpret_cast<const float4*>(in1)[i];
        int c4 = i & (DK / 4 - 1);
        float4 w = reinterpret_cast<const float4*>(weight + (size_t)(*type_index) * DK)[c4];
        ushort4 o;
        o.x = f2bf(v.x * w.x);
        o.y = f2bf(v.y * w.y);
        o.z = f2bf(v.z * w.z);
        o.w = f2bf(v.w * w.w);
        reinterpret_cast<ushort4*>(a_bf)[i] = o;
    } else {
        int j = i - QA;
        float4 v = reinterpret_cast<const float4*>(in2)[j];
        ushort4 o;
        o.x = f2bf(v.x);
        o.y = f2bf(v.y);
        o.z = f2bf(v.z);
        o.w = f2bf(v.w);
        reinterpret_cast<ushort4*>(b_bf)[j] = o;
    }
}

// NT GEMM: C[m][n] = sum_k A[m][k]*B[n][k] + bias. A,B bf16 row-major [*,DK].
// Block 256 thr = 4 waves; 128x128 C-tile; each wave a 64x64 sub-tile via
// 4x4 of mfma_f32_16x16x32_bf16, BK=64 (2 k-slices per tile).
__global__ __launch_bounds__(256) void gemm_bt(
        const unsigned short* __restrict__ A, const unsigned short* __restrict__ B,
        const float* __restrict__ bias, float* __restrict__ C) {
    __shared__ __align__(16) unsigned short ldsA[BM * BK];  // 16 KB
    __shared__ __align__(16) unsigned short ldsB[BN * BK];  // 16 KB

    const int tid  = threadIdx.x;
    const int wave = tid >> 6;
    const int lane = tid & 63;
    const int quad = lane >> 4;
    const int r16  = lane & 15;
    const int wm   = wave & 1;   // wave's M half
    const int wn   = wave >> 1;  // wave's N half

    // XCD-aware swizzle: blocks dispatch round-robin over 8 XCDs (bid&7).
    // Give each XCD an 8-block-wide column stripe; its ~96 co-resident blocks
    // then form a ~12x8 region: 12 A-panels + 8 B-panels ~ 2.6 MB < 4 MB L2,
    // and the XCD's 8 B-panels stay L2-resident for the whole kernel.
    const int bid   = blockIdx.x;
    const int xcd   = bid & 7;
    const int inner = bid >> 3;          // 0..511
    const int tn    = xcd * 8 + (inner & 7);
    const int tm    = inner >> 3;        // 0..63
    const int bm = tm * BM;
    const int bn = tn * BN;

    f32x4 acc[4][4];
#pragma unroll
    for (int i = 0; i < 4; ++i)
#pragma unroll
        for (int j = 0; j < 4; ++j)
            acc[i][j] = (f32x4){0.f, 0.f, 0.f, 0.f};

    // Staging (BK=64): each wave fills 32 tile-rows via 4 calls; call c covers
    // rows [wave*32 + c*8, +8), lane -> row += lane>>3, col (lane&7)*8.
    // LDS layout row-major [row][BK]; dest = wave/c base + lane*16B (granule
    // index row*8 + colq == base + lane) — matches the wave-uniform-base rule.
    const int srow = wave * 32 + (lane >> 3);
    const int scol = (lane & 7) * 8;
    const unsigned short* ag = A + (size_t)(bm + srow) * DK + scol;
    const unsigned short* bg = B + (size_t)(bn + srow) * DK + scol;
    unsigned short* la = &ldsA[wave * 32 * BK];
    unsigned short* lb = &ldsB[wave * 32 * BK];

    for (int kt = 0; kt < DK; kt += BK) {
#pragma unroll
        for (int c = 0; c < 4; ++c) {
            __builtin_amdgcn_global_load_lds(ag + kt + (size_t)(c * 8) * DK, la + c * 8 * BK, 16, 0, 0);
            __builtin_amdgcn_global_load_lds(bg + kt + (size_t)(c * 8) * DK, lb + c * 8 * BK, 16, 0, 0);
        }
        __syncthreads();

#pragma unroll
        for (int ks = 0; ks < 2; ++ks) {
            // A-operand frag: A[m=16-row][k=quad*8+j] -> 16B at (row, ks*32+quad*8)
            bf16x8 af[4], bfr[4];
#pragma unroll
            for (int mi = 0; mi < 4; ++mi)
                af[mi] = *(const bf16x8*)&ldsA[(wm * 64 + mi * 16 + r16) * BK + ks * 32 + quad * 8];
#pragma unroll
            for (int ni = 0; ni < 4; ++ni)
                bfr[ni] = *(const bf16x8*)&ldsB[(wn * 64 + ni * 16 + r16) * BK + ks * 32 + quad * 8];

#pragma unroll
            for (int mi = 0; mi < 4; ++mi)
#pragma unroll
                for (int ni = 0; ni < 4; ++ni)
                    acc[mi][ni] = __builtin_amdgcn_mfma_f32_16x16x32_bf16(
                        af[mi], bfr[ni], acc[mi][ni], 0, 0, 0);
        }
        __syncthreads();
    }

    // Epilogue: C/D mapping col=lane&15, row=quad*4+reg (verified m89/m91).
    const float bv = bias[0];
#pragma unroll
    for (int mi = 0; mi < 4; ++mi) {
        const int row0 = bm + wm * 64 + mi * 16 + quad * 4;
#pragma unroll
        for (int ni = 0; ni < 4; ++ni) {
            const int col = bn + wn * 64 + ni * 16 + r16;
#pragma unroll
            for (int r = 0; r < 4; ++r)
                C[(size_t)(row0 + r) * N2 + col] = acc[mi][ni][r] + bv;
        }
    }
}

// Fallback if workspace is too small for the bf16 copies (correct but slow).
__global__ void naive_kernel(const float* __restrict__ in1, const float* __restrict__ in2,
                             const float* __restrict__ weight, const int* __restrict__ type_index,
                             const float* __restrict__ bias, float* __restrict__ out) {
    int col = blockIdx.x * 16 + threadIdx.x;
    int row = blockIdx.y * 16 + threadIdx.y;
    const float* wr = weight + (size_t)(*type_index) * DK;
    float s = 0.f;
    for (int k = 0; k < DK; ++k)
        s += in1[(size_t)row * DK + k] * wr[k] * in2[(size_t)col * DK + k];
    out[(size_t)row * N2 + col] = s + bias[0];
}

extern "C" void kernel_launch(void* const* d_in, const int* in_sizes, int n_in,
                              void* d_out, int out_size, void* d_ws, size_t ws_size,
                              hipStream_t stream) {
    const float* in1  = (const float*)d_in[0];
    const float* in2  = (const float*)d_in[1];
    const float* wgt  = (const float*)d_in[2];
    const float* bias = (const float*)d_in[3];
    const int*   tix  = (const int*)d_in[4];
    float* out = (float*)d_out;

    const size_t need = 2ull * (N1 + N2) * DK;  // bf16 copies of A(scaled)+B = 16 MB
    if (ws_size >= need) {
        unsigned short* a_bf = (unsigned short*)d_ws;
        unsigned short* b_bf = a_bf + (size_t)N1 * DK;

        const int total4 = (N1 + N2) * DK / 4;
        convert_kernel<<<total4 / 256, 256, 0, stream>>>(in1, in2, wgt, tix, a_bf, b_bf);

        gemm_bt<<<(N1 / BM) * (N2 / BN), 256, 0, stream>>>(a_bf, b_bf, bias, out);
    } else {
        dim3 grid(N2 / 16, N1 / 16);
        dim3 blk(16, 16);
        naive_kernel<<<grid, blk, 0, stream>>>(in1, in2, wgt, tix, bias, out);
    }
}